// Round 3
// baseline (464.633 us; speedup 1.0000x reference)
//
#include <hip/hip_runtime.h>

// Problem constants
#define B_   4
#define O_   1000
#define R_   20000
#define NF_  6
#define EDP_ 128   // ED=100 padded to 128
#define KS_  25    // k-split for aggregation
#define CHUNK_ 800 // R_/KS_
#define MPAD_ 1024 // M=1000 padded

// ws layout (in floats):
//   Et  : [4][128][20000] bf16     = 10,240,000 bf16 = 5,120,000 float slots
//   part: [25][4][1024][128] f32   = 13,107,200 floats
//   Wt  : ALIASES head of part region. Written by k_prep, read by k_mlp,
//         then overwritten by k_agg (stream-serial => safe).
#define ET_OFF   0
#define PART_OFF 5120000
#define WT_USHORTS (4 * 2 * 25600)

typedef short bf16x8 __attribute__((ext_vector_type(8)));
typedef float f32x4  __attribute__((ext_vector_type(4)));
typedef unsigned short ushort4v __attribute__((ext_vector_type(4)));
typedef unsigned short ushort8v __attribute__((ext_vector_type(8)));

#define MFMA16 __builtin_amdgcn_mfma_f32_16x16x32_bf16

__device__ __forceinline__ unsigned short f2bf(float x) {
    union { float f; unsigned int u; } v; v.f = x;
    unsigned int r = (v.u + 0x7FFFu + ((v.u >> 16) & 1u)) >> 16;  // RNE
    return (unsigned short)r;
}

__device__ __forceinline__ float bf2f(unsigned short h) {
    union { unsigned int u; float f; } v; v.u = (unsigned int)h << 16;
    return v.f;
}

// ---------------- Kernel 0: weight prep (bf16 hi/lo transposed) -------------
__global__ __launch_bounds__(256) void k_prep(
    const float* __restrict__ rw1, const float* __restrict__ rb1,
    const float* __restrict__ rw2, const float* __restrict__ rb2,
    const float* __restrict__ rw3, const float* __restrict__ rb3,
    const float* __restrict__ rw4, const float* __restrict__ rb4,
    unsigned short* __restrict__ Wt, float* __restrict__ bfp)
{
    const int l = blockIdx.y;
    const float* Ws[4] = {rw1, rw2, rw3, rw4};
    const float* Bs[4] = {rb1, rb2, rb3, rb4};
    const int   Ksz[4] = {13, 150, 150, 150};
    const int   Nsz[4] = {150, 150, 150, 100};
    const float* w = Ws[l];
    const int K = Ksz[l], N = Nsz[l];

    int idx = blockIdx.x * 256 + threadIdx.x;   // 0..25599
    if (idx < 25600) {
        int n = idx / 160, k = idx % 160;
        float v = (k < K && n < N) ? w[k * N + n] : 0.f;
        unsigned short h = f2bf(v);
        unsigned short lo = f2bf(v - bf2f(h));
        Wt[(size_t)l * 51200 + idx]         = h;
        Wt[(size_t)l * 51200 + 25600 + idx] = lo;
    }
    if (blockIdx.x == 0 && threadIdx.x < 160)
        bfp[l * 160 + threadIdx.x] = (threadIdx.x < (unsigned)N) ? Bs[l][threadIdx.x] : 0.f;
}

// ---------------- Kernel 1: fused marshalling + relational MLP --------------
// grid (313, 4): block = 64 r-rows of batch b (last block clamps rows).
// Phase 1 (marshal): 4 waves split n=1000 (250 each); lane = r-row.
//   ss/rs partials -> psum LDS -> reduced into layer-1 input (hi/lo split).
// Phase 2: 4-layer MLP via bf16 MFMA with split-weight pseudo-fp32.
template<int NT>
__device__ __forceinline__ void layer_mm(
    const unsigned short (*act)[168],
    const unsigned short* __restrict__ Wh, const unsigned short* __restrict__ Wl,
    int arow, int koff, int cl, f32x4* acc)
{
    #pragma unroll
    for (int n = 0; n < NT; ++n) acc[n] = (f32x4){0.f, 0.f, 0.f, 0.f};
    #pragma unroll
    for (int ks = 0; ks < 5; ++ks) {
        bf16x8 a = *(const bf16x8*)&act[arow][ks * 32 + koff];
        #pragma unroll
        for (int n = 0; n < NT; ++n) {
            bf16x8 wh = *(const bf16x8*)(Wh + (size_t)(n * 16 + cl) * 160 + ks * 32 + koff);
            bf16x8 wl = *(const bf16x8*)(Wl + (size_t)(n * 16 + cl) * 160 + ks * 32 + koff);
            acc[n] = MFMA16(a, wh, acc[n], 0, 0, 0);
            acc[n] = MFMA16(a, wl, acc[n], 0, 0, 0);
        }
    }
}

template<int NT>
__device__ __forceinline__ void epi(
    f32x4* acc, const float* __restrict__ bias,
    unsigned short (*out)[168], int m0, int cl, int rg0)
{
    __syncthreads();   // all waves done reading input acts
    #pragma unroll
    for (int n = 0; n < NT; ++n) {
        int col = n * 16 + cl;
        float bv = bias[col];
        #pragma unroll
        for (int rg = 0; rg < 4; ++rg) {
            float v = fmaxf(acc[n][rg] + bv, 0.f);
            out[m0 + rg0 + rg][col] = f2bf(v);
        }
    }
    __syncthreads();
}

__global__ __launch_bounds__(256) void k_mlp(
    const float* __restrict__ obj, const float* __restrict__ S,
    const float* __restrict__ RRm, const float* __restrict__ rinfo,
    unsigned short* __restrict__ Et,
    const unsigned short* __restrict__ Wt, const float* __restrict__ bfp)
{
    __shared__ unsigned short act[64][168];   // single buffer, in-place layers
    __shared__ unsigned short alo[64][32];    // lo part of layer-1 input
    __shared__ float psum[4][64][12];         // per-wave marshal partials
    const int t  = threadIdx.x;
    const int b  = blockIdx.y;
    const int r0 = blockIdx.x * 64;           // 0..19968 (last block clamps)

    // ---- phase 1: marshal (senders/receivers einsum over n)
    {
        const int rl = t & 63;
        const int w  = t >> 6;
        int rme = r0 + rl; if (rme > R_ - 1) rme = R_ - 1;
        const float* Sp = S   + (size_t)b * O_ * R_ + (size_t)(w * 250) * R_ + rme;
        const float* Rp = RRm + (size_t)b * O_ * R_ + (size_t)(w * 250) * R_ + rme;
        const float* ob = obj + ((size_t)b * O_ + (size_t)(w * 250)) * NF_;
        float ss[6] = {0.f,0.f,0.f,0.f,0.f,0.f};
        float rs[6] = {0.f,0.f,0.f,0.f,0.f,0.f};
        #pragma unroll 2
        for (int n = 0; n < 250; ++n) {
            float sv = Sp[(size_t)n * R_];
            float rv = Rp[(size_t)n * R_];
            #pragma unroll
            for (int f = 0; f < 6; ++f) {
                float o = ob[n * NF_ + f];
                ss[f] = fmaf(sv, o, ss[f]);
                rs[f] = fmaf(rv, o, rs[f]);
            }
        }
        #pragma unroll
        for (int f = 0; f < 6; ++f) {
            psum[w][rl][f]     = ss[f];
            psum[w][rl][6 + f] = rs[f];
        }
    }
    __syncthreads();

    // ---- build layer-1 input: reduce 4 wave-partials, hi/lo split, pad to 32
    for (int idx = t; idx < 64 * 32; idx += 256) {
        int rr = idx >> 5, k = idx & 31;
        float v = 0.f;
        if (k < 12) {
            v = psum[0][rr][k] + psum[1][rr][k] + psum[2][rr][k] + psum[3][rr][k];
        } else if (k == 12) {
            int r = r0 + rr; if (r > R_ - 1) r = R_ - 1;
            v = rinfo[(size_t)b * R_ + r];
        }
        unsigned short h = f2bf(v);
        act[rr][k] = h;
        alo[rr][k] = f2bf(v - bf2f(h));
    }
    __syncthreads();

    // ---- phase 2: MLP
    const int lane = t & 63, wave = t >> 6;
    const int m0   = wave * 16;
    const int arow = m0 + (lane & 15);
    const int koff = (lane >> 4) * 8;
    const int cl   = lane & 15;
    const int rg0  = (lane >> 4) * 4;

    f32x4 acc[10];

    // layer 1: K=32 (1 k-step), split A and split W (3 MFMA / tile)
    {
        const unsigned short* Wh = Wt;
        const unsigned short* Wl = Wt + 25600;
        bf16x8 ah = *(const bf16x8*)&act[arow][koff];
        bf16x8 al = *(const bf16x8*)&alo[arow][koff];
        #pragma unroll
        for (int n = 0; n < 10; ++n) {
            bf16x8 wh = *(const bf16x8*)(Wh + (size_t)(n * 16 + cl) * 160 + koff);
            bf16x8 wl = *(const bf16x8*)(Wl + (size_t)(n * 16 + cl) * 160 + koff);
            f32x4 a = (f32x4){0.f, 0.f, 0.f, 0.f};
            a = MFMA16(ah, wh, a, 0, 0, 0);
            a = MFMA16(ah, wl, a, 0, 0, 0);
            a = MFMA16(al, wh, a, 0, 0, 0);
            acc[n] = a;
        }
    }
    epi<10>(acc, bfp + 0 * 160, act, m0, cl, rg0);

    layer_mm<10>(act, Wt + 1 * 51200, Wt + 1 * 51200 + 25600, arow, koff, cl, acc);
    epi<10>(acc, bfp + 1 * 160, act, m0, cl, rg0);

    layer_mm<10>(act, Wt + 2 * 51200, Wt + 2 * 51200 + 25600, arow, koff, cl, acc);
    epi<10>(acc, bfp + 2 * 160, act, m0, cl, rg0);

    layer_mm<7>(act, Wt + 3 * 51200, Wt + 3 * 51200 + 25600, arow, koff, cl, acc);
    epi<7>(acc, bfp + 3 * 160, act, m0, cl, rg0);

    // write E transposed bf16: Et[b][j][r], rows j=100..127 zeroed
    for (int idx = t; idx < 64 * 128; idx += 256) {
        int rr = idx & 63, j = idx >> 6;
        int r = r0 + rr;
        if (r < R_)
            Et[((size_t)(b * EDP_ + j)) * R_ + r] = (j < 100) ? act[rr][j] : (unsigned short)0;
    }
}

// ---------------- Kernel 3: aggregation, M=128 per block --------------------
// per (mt, b, kz): C[128x128] += RR[128 x 800] @ E[800 x 128]
// grid (8, 4, 25), 256 threads = 4 waves; wave w owns rows w*32..w*32+31
// (two 16-row m-groups), all 128 cols (8 n-tiles).
// A: direct per-lane global loads (+f2bf). B: double-buffered LDS
// [2][128][36] (18.4 KB), one barrier per k-step of 32, loads issued early.
__global__ __launch_bounds__(256) void k_agg(
    const float* __restrict__ RRm, const unsigned short* __restrict__ Et,
    float* __restrict__ part)
{
    __shared__ unsigned short sB[2][128][36];   // pad 36: 18-dword row stride
    const int t = threadIdx.x;
    const int mt = blockIdx.x, b = blockIdx.y, kz = blockIdx.z;
    const int lane = t & 63, wave = t >> 6;
    const int k0 = kz * CHUNK_;

    // B-stage: 128 rows x 32 bf16 per k-step = 512 x 16B chunks; 2 per thread
    const int br0 = t >> 2, bc0 = (t & 3) * 8;       // rows 0..63
    const int br1 = br0 + 64;                        // rows 64..127
    const unsigned short* EtB = Et + (size_t)b * EDP_ * R_;

    // A: two per-lane rows (m-groups), clamped (rows >=1000 dup 999; their
    // part rows are padding, never read by k_obj)
    const int cl = lane & 15, koff = (lane >> 4) * 8;
    int n0 = mt * 128 + wave * 32 + cl;
    int n1 = n0 + 16;
    if (n0 > 999) n0 = 999;
    if (n1 > 999) n1 = 999;
    const float* Ap0 = RRm + ((size_t)(b * O_) + n0) * R_ + k0 + koff;
    const float* Ap1 = RRm + ((size_t)(b * O_) + n1) * R_ + k0 + koff;

    f32x4 acc[2][8] = {};
    float4 a0c, a1c, a2c, a3c;
    float4 a0n = {0,0,0,0}, a1n = {0,0,0,0}, a2n = {0,0,0,0}, a3n = {0,0,0,0};

    // prologue: stage B + load A for iter 0
    {
        ushort8v v0 = *(const ushort8v*)(EtB + (size_t)br0 * R_ + k0 + bc0);
        ushort8v v1 = *(const ushort8v*)(EtB + (size_t)br1 * R_ + k0 + bc0);
        *(ushort8v*)&sB[0][br0][bc0] = v0;
        *(ushort8v*)&sB[0][br1][bc0] = v1;
        a0c = *(const float4*)(Ap0 + 0);
        a1c = *(const float4*)(Ap0 + 4);
        a2c = *(const float4*)(Ap1 + 0);
        a3c = *(const float4*)(Ap1 + 4);
    }
    __syncthreads();

    for (int it = 0; it < CHUNK_ / 32; ++it) {
        const int cur = it & 1, nxt = cur ^ 1;
        const bool more = (it + 1 < CHUNK_ / 32);
        ushort8v v0, v1;
        if (more) {
            // issue next-iter loads EARLY (hide HBM latency under MFMA phase)
            const int kb = k0 + (it + 1) * 32;
            v0 = *(const ushort8v*)(EtB + (size_t)br0 * R_ + kb + bc0);
            v1 = *(const ushort8v*)(EtB + (size_t)br1 * R_ + kb + bc0);
            a0n = *(const float4*)(Ap0 + (it + 1) * 32);
            a1n = *(const float4*)(Ap0 + (it + 1) * 32 + 4);
            a2n = *(const float4*)(Ap1 + (it + 1) * 32);
            a3n = *(const float4*)(Ap1 + (it + 1) * 32 + 4);
        }
        // convert A (cur) to bf16 fragments
        bf16x8 af0, af1;
        af0[0] = (short)f2bf(a0c.x); af0[1] = (short)f2bf(a0c.y);
        af0[2] = (short)f2bf(a0c.z); af0[3] = (short)f2bf(a0c.w);
        af0[4] = (short)f2bf(a1c.x); af0[5] = (short)f2bf(a1c.y);
        af0[6] = (short)f2bf(a1c.z); af0[7] = (short)f2bf(a1c.w);
        af1[0] = (short)f2bf(a2c.x); af1[1] = (short)f2bf(a2c.y);
        af1[2] = (short)f2bf(a2c.z); af1[3] = (short)f2bf(a2c.w);
        af1[4] = (short)f2bf(a3c.x); af1[5] = (short)f2bf(a3c.y);
        af1[6] = (short)f2bf(a3c.z); af1[7] = (short)f2bf(a3c.w);
        #pragma unroll
        for (int ni = 0; ni < 8; ++ni) {
            bf16x8 bf = *(const bf16x8*)&sB[cur][ni * 16 + cl][koff];
            acc[0][ni] = MFMA16(af0, bf, acc[0][ni], 0, 0, 0);
            acc[1][ni] = MFMA16(af1, bf, acc[1][ni], 0, 0, 0);
        }
        if (more) {
            *(ushort8v*)&sB[nxt][br0][bc0] = v0;
            *(ushort8v*)&sB[nxt][br1][bc0] = v1;
        }
        __syncthreads();
        a0c = a0n; a1c = a1n; a2c = a2n; a3c = a3n;
    }

    // store partials: C/D layout col=lane&15, row=(lane>>4)*4+rg
    float* pp = part + ((size_t)(kz * 4 + b) * MPAD_) * 128;
    #pragma unroll
    for (int mg = 0; mg < 2; ++mg) {
        const int rowb = mt * 128 + wave * 32 + mg * 16 + (lane >> 4) * 4;
        #pragma unroll
        for (int ni = 0; ni < 8; ++ni)
            #pragma unroll
            for (int rg = 0; rg < 4; ++rg)
                pp[(size_t)(rowb + rg) * 128 + ni * 16 + cl] = acc[mg][ni][rg];
    }
}

// ---------------- Kernel 4: object MLP (sums agg partials) ------------------
__global__ __launch_bounds__(256) void k_obj(
    const float* __restrict__ obj, const float* __restrict__ part,
    const float* __restrict__ ow1, const float* __restrict__ ob1,
    const float* __restrict__ ow2, const float* __restrict__ ob2,
    float* __restrict__ out)
{
    __shared__ float C[8][112];
    __shared__ float h[8][104];
    const int t = threadIdx.x;
    const int g0 = blockIdx.x * 8;

    for (int idx = t; idx < 8 * NF_; idx += 256) {
        int rr = idx / NF_, f = idx % NF_;
        C[rr][f] = obj[(size_t)(g0 + rr) * NF_ + f];
    }
    for (int idx = t; idx < 8 * 100; idx += 256) {
        int rr = idx / 100, f = idx % 100;
        int g = g0 + rr, b = g / 1000, n = g % 1000;
        float s = 0.f;
        for (int z = 0; z < KS_; ++z)
            s += part[((size_t)(z * 4 + b) * MPAD_ + n) * 128 + f];
        C[rr][6 + f] = s;
    }
    __syncthreads();

    for (int idx = t; idx < 8 * 100; idx += 256) {
        int rr = idx / 100, j = idx % 100;
        float acc = ob1[j];
        for (int k = 0; k < 106; ++k)
            acc = fmaf(C[rr][k], ow1[k * 100 + j], acc);
        h[rr][j] = fmaxf(acc, 0.f);
    }
    __syncthreads();

    if (t < 16) {
        int rr = t >> 1, j = t & 1;
        float acc = ob2[j];
        for (int k = 0; k < 100; ++k)
            acc = fmaf(h[rr][k], ow2[k * 2 + j], acc);
        out[(size_t)(g0 + rr) * 2 + j] = acc;
    }
}

// ---------------- launch ----------------------------------------------------
extern "C" void kernel_launch(void* const* d_in, const int* in_sizes, int n_in,
                              void* d_out, int out_size, void* d_ws, size_t ws_size,
                              hipStream_t stream)
{
    const float* obj   = (const float*)d_in[0];
    const float* S     = (const float*)d_in[1];
    const float* RRm   = (const float*)d_in[2];
    const float* rinfo = (const float*)d_in[3];
    const float* rw1   = (const float*)d_in[4];
    const float* rb1   = (const float*)d_in[5];
    const float* rw2   = (const float*)d_in[6];
    const float* rb2   = (const float*)d_in[7];
    const float* rw3   = (const float*)d_in[8];
    const float* rb3   = (const float*)d_in[9];
    const float* rw4   = (const float*)d_in[10];
    const float* rb4   = (const float*)d_in[11];
    const float* ow1   = (const float*)d_in[12];
    const float* ob1   = (const float*)d_in[13];
    const float* ow2   = (const float*)d_in[14];
    const float* ob2   = (const float*)d_in[15];

    float* ws            = (float*)d_ws;
    unsigned short* Et   = (unsigned short*)(ws + ET_OFF);
    float* part          = ws + PART_OFF;
    unsigned short* Wt   = (unsigned short*)(ws + PART_OFF);  // aliases part head
    float* bfp           = ws + PART_OFF + (WT_USHORTS / 2);
    float* out           = (float*)d_out;

    k_prep<<<dim3(100, 4), 256, 0, stream>>>(rw1, rb1, rw2, rb2, rw3, rb3, rw4, rb4,
                                             Wt, bfp);
    k_mlp<<<dim3(313, 4), 256, 0, stream>>>(obj, S, RRm, rinfo, Et, Wt, bfp);
    k_agg<<<dim3(8, 4, KS_), 256, 0, stream>>>(RRm, Et, part);
    k_obj<<<dim3(500), 256, 0, stream>>>(obj, part, ow1, ob1, ow2, ob2, out);
}

// Round 4
// 381.822 us; speedup vs baseline: 1.2169x; 1.2169x over previous
//
#include <hip/hip_runtime.h>

// Problem constants
#define B_   4
#define O_   1000
#define R_   20000
#define NF_  6
#define EDP_ 128   // ED=100 padded to 128
#define KS_  25    // k-split for aggregation
#define CHUNK_ 800 // R_/KS_
#define MPAD_ 1024 // M=1000 padded

// ws layout (in floats) — identical footprint to the verified round-0/1 layout:
//   bmp : [2][80000][16]           = 2,560,000 floats
//   Et  : [4][128][20000] bf16     = 10,240,000 bf16 = 5,120,000 float slots
//   part: [25][4][1024][128] f32   = 13,107,200 floats
//   Wt  : ALIASES head of part region. Written by k_prep, read by k_mlp,
//         then overwritten by k_agg (stream-serial => safe).
#define ET_OFF   2560000
#define PART_OFF 7680000
#define WT_USHORTS (4 * 2 * 25600)

typedef short bf16x8 __attribute__((ext_vector_type(8)));
typedef float f32x4  __attribute__((ext_vector_type(4)));
typedef unsigned short ushort4v __attribute__((ext_vector_type(4)));
typedef unsigned short ushort8v __attribute__((ext_vector_type(8)));

#define MFMA16 __builtin_amdgcn_mfma_f32_16x16x32_bf16

__device__ __forceinline__ unsigned short f2bf(float x) {
    union { float f; unsigned int u; } v; v.f = x;
    unsigned int r = (v.u + 0x7FFFu + ((v.u >> 16) & 1u)) >> 16;  // RNE
    return (unsigned short)r;
}

__device__ __forceinline__ float bf2f(unsigned short h) {
    union { unsigned int u; float f; } v; v.u = (unsigned int)h << 16;
    return v.f;
}

// ---------------- Kernel 0: weight prep (bf16 hi/lo transposed) -------------
__global__ __launch_bounds__(256) void k_prep(
    const float* __restrict__ rw1, const float* __restrict__ rb1,
    const float* __restrict__ rw2, const float* __restrict__ rb2,
    const float* __restrict__ rw3, const float* __restrict__ rb3,
    const float* __restrict__ rw4, const float* __restrict__ rb4,
    unsigned short* __restrict__ Wt, float* __restrict__ bfp)
{
    const int l = blockIdx.y;
    const float* Ws[4] = {rw1, rw2, rw3, rw4};
    const float* Bs[4] = {rb1, rb2, rb3, rb4};
    const int   Ksz[4] = {13, 150, 150, 150};
    const int   Nsz[4] = {150, 150, 150, 100};
    const float* w = Ws[l];
    const int K = Ksz[l], N = Nsz[l];

    int idx = blockIdx.x * 256 + threadIdx.x;   // 0..25599
    if (idx < 25600) {
        int n = idx / 160, k = idx % 160;
        float v = (k < K && n < N) ? w[k * N + n] : 0.f;
        unsigned short h = f2bf(v);
        unsigned short lo = f2bf(v - bf2f(h));
        Wt[(size_t)l * 51200 + idx]         = h;
        Wt[(size_t)l * 51200 + 25600 + idx] = lo;
    }
    if (blockIdx.x == 0 && threadIdx.x < 160)
        bfp[l * 160 + threadIdx.x] = (threadIdx.x < (unsigned)N) ? Bs[l][threadIdx.x] : 0.f;
}

// ---------------- Kernel 1: marshalling, 4-deep load pipeline ---------------
// grid (79, 4, 2), 256 thr. Thread = one r-column; loop over 500 n with an
// explicit depth-4 software pipeline (8 loads in flight during FMA block).
__global__ __launch_bounds__(256) void k_marshal(
    const float* __restrict__ obj, const float* __restrict__ S,
    const float* __restrict__ RRm, const float* __restrict__ rinfo,
    float* __restrict__ bmp)
{
    __shared__ float sobj[500 * NF_];
    const int b = blockIdx.y, z = blockIdx.z;
    const int n0 = z * 500;
    for (int i = threadIdx.x; i < 500 * NF_; i += 256)
        sobj[i] = obj[(size_t)b * O_ * NF_ + (size_t)n0 * NF_ + i];
    __syncthreads();

    const int r = blockIdx.x * 256 + threadIdx.x;
    if (r >= R_) return;

    const size_t base = (size_t)b * O_ * R_ + (size_t)n0 * R_ + r;
    const float* Sp = S + base;
    const float* Rp = RRm + base;

    float ss[NF_] = {0.f, 0.f, 0.f, 0.f, 0.f, 0.f};
    float rs[NF_] = {0.f, 0.f, 0.f, 0.f, 0.f, 0.f};

    // prologue: current group n=0..3
    float cs0 = Sp[0], cs1 = Sp[(size_t)R_], cs2 = Sp[2 * (size_t)R_], cs3 = Sp[3 * (size_t)R_];
    float cr0 = Rp[0], cr1 = Rp[(size_t)R_], cr2 = Rp[2 * (size_t)R_], cr3 = Rp[3 * (size_t)R_];

    for (int n = 0; n < 500; n += 4) {
        float ns0, ns1, ns2, ns3, nr0, nr1, nr2, nr3;
        const bool more = (n + 4 < 500);
        if (more) {
            const float* Sn = Sp + (size_t)(n + 4) * R_;
            const float* Rn = Rp + (size_t)(n + 4) * R_;
            ns0 = Sn[0]; ns1 = Sn[(size_t)R_]; ns2 = Sn[2 * (size_t)R_]; ns3 = Sn[3 * (size_t)R_];
            nr0 = Rn[0]; nr1 = Rn[(size_t)R_]; nr2 = Rn[2 * (size_t)R_]; nr3 = Rn[3 * (size_t)R_];
        }
        const float* ob = &sobj[n * NF_];
        #pragma unroll
        for (int f = 0; f < NF_; ++f) {
            float o0 = ob[f], o1 = ob[NF_ + f], o2 = ob[2 * NF_ + f], o3 = ob[3 * NF_ + f];
            ss[f] = fmaf(cs3, o3, fmaf(cs2, o2, fmaf(cs1, o1, fmaf(cs0, o0, ss[f]))));
            rs[f] = fmaf(cr3, o3, fmaf(cr2, o2, fmaf(cr1, o1, fmaf(cr0, o0, rs[f]))));
        }
        if (more) {
            cs0 = ns0; cs1 = ns1; cs2 = ns2; cs3 = ns3;
            cr0 = nr0; cr1 = nr1; cr2 = nr2; cr3 = nr3;
        }
    }

    float* outp = bmp + ((size_t)z * 80000 + (size_t)b * R_ + r) * 16;
    #pragma unroll
    for (int f = 0; f < NF_; ++f) {
        outp[f]     = ss[f];
        outp[6 + f] = rs[f];
    }
    outp[12] = (z == 0) ? rinfo[(size_t)b * R_ + r] : 0.f;
}

// ---------------- Kernel 2: relational MLP via bf16 MFMA --------------------
template<int NT>
__device__ __forceinline__ void layer_mm(
    const unsigned short (*act)[168],
    const unsigned short* __restrict__ Wh, const unsigned short* __restrict__ Wl,
    int arow, int koff, int cl, f32x4* acc)
{
    #pragma unroll
    for (int n = 0; n < NT; ++n) acc[n] = (f32x4){0.f, 0.f, 0.f, 0.f};
    #pragma unroll
    for (int ks = 0; ks < 5; ++ks) {
        bf16x8 a = *(const bf16x8*)&act[arow][ks * 32 + koff];
        #pragma unroll
        for (int n = 0; n < NT; ++n) {
            bf16x8 wh = *(const bf16x8*)(Wh + (size_t)(n * 16 + cl) * 160 + ks * 32 + koff);
            bf16x8 wl = *(const bf16x8*)(Wl + (size_t)(n * 16 + cl) * 160 + ks * 32 + koff);
            acc[n] = MFMA16(a, wh, acc[n], 0, 0, 0);
            acc[n] = MFMA16(a, wl, acc[n], 0, 0, 0);
        }
    }
}

template<int NT>
__device__ __forceinline__ void epi(
    f32x4* acc, const float* __restrict__ bias,
    unsigned short (*out)[168], int m0, int cl, int rg0)
{
    __syncthreads();   // all waves done reading input acts
    #pragma unroll
    for (int n = 0; n < NT; ++n) {
        int col = n * 16 + cl;
        float bv = bias[col];
        #pragma unroll
        for (int rg = 0; rg < 4; ++rg) {
            float v = fmaxf(acc[n][rg] + bv, 0.f);
            out[m0 + rg0 + rg][col] = f2bf(v);
        }
    }
    __syncthreads();
}

__global__ __launch_bounds__(256) void k_mlp(
    const float* __restrict__ bmp, unsigned short* __restrict__ Et,
    const unsigned short* __restrict__ Wt, const float* __restrict__ bfp)
{
    __shared__ unsigned short act[64][168];   // single buffer, in-place layers
    __shared__ unsigned short alo[64][32];    // lo part of layer-1 input
    const int t = threadIdx.x;
    const size_t row0 = (size_t)blockIdx.x * 64;

    for (int idx = t; idx < 64 * 32; idx += 256) {
        int rr = idx >> 5, k = idx & 31;
        float v = 0.f;
        if (k < 13)
            v = bmp[(row0 + rr) * 16 + k]
              + bmp[(size_t)80000 * 16 + (row0 + rr) * 16 + k];
        unsigned short h = f2bf(v);
        act[rr][k] = h;
        alo[rr][k] = f2bf(v - bf2f(h));
    }
    __syncthreads();

    const int lane = t & 63, wave = t >> 6;
    const int m0   = wave * 16;
    const int arow = m0 + (lane & 15);
    const int koff = (lane >> 4) * 8;
    const int cl   = lane & 15;
    const int rg0  = (lane >> 4) * 4;

    f32x4 acc[10];

    // layer 1: K=32 (1 k-step), split A and split W (3 MFMA / tile)
    {
        const unsigned short* Wh = Wt;
        const unsigned short* Wl = Wt + 25600;
        bf16x8 ah = *(const bf16x8*)&act[arow][koff];
        bf16x8 al = *(const bf16x8*)&alo[arow][koff];
        #pragma unroll
        for (int n = 0; n < 10; ++n) {
            bf16x8 wh = *(const bf16x8*)(Wh + (size_t)(n * 16 + cl) * 160 + koff);
            bf16x8 wl = *(const bf16x8*)(Wl + (size_t)(n * 16 + cl) * 160 + koff);
            f32x4 a = (f32x4){0.f, 0.f, 0.f, 0.f};
            a = MFMA16(ah, wh, a, 0, 0, 0);
            a = MFMA16(ah, wl, a, 0, 0, 0);
            a = MFMA16(al, wh, a, 0, 0, 0);
            acc[n] = a;
        }
    }
    epi<10>(acc, bfp + 0 * 160, act, m0, cl, rg0);

    layer_mm<10>(act, Wt + 1 * 51200, Wt + 1 * 51200 + 25600, arow, koff, cl, acc);
    epi<10>(acc, bfp + 1 * 160, act, m0, cl, rg0);

    layer_mm<10>(act, Wt + 2 * 51200, Wt + 2 * 51200 + 25600, arow, koff, cl, acc);
    epi<10>(acc, bfp + 2 * 160, act, m0, cl, rg0);

    layer_mm<7>(act, Wt + 3 * 51200, Wt + 3 * 51200 + 25600, arow, koff, cl, acc);
    epi<7>(acc, bfp + 3 * 160, act, m0, cl, rg0);

    // write E transposed bf16: Et[b][j][r], rows j=100..127 zeroed
    for (int idx = t; idx < 64 * 128; idx += 256) {
        int rr = idx & 63, j = idx >> 6;
        size_t gr = row0 + rr;
        int b = (int)(gr / R_);
        int r = (int)(gr - (size_t)b * R_);
        Et[((size_t)(b * EDP_ + j)) * R_ + r] = (j < 100) ? act[rr][j] : (unsigned short)0;
    }
}

// ---------------- Kernel 3: aggregation, M=128 per block --------------------
// per (mt, b, kz): C[128x128] += RR[128 x 800] @ E[800 x 128]
// grid (8, 4, 25), 256 threads = 4 waves; wave w owns rows w*32..w*32+31
// (two 16-row m-groups), all 128 cols (8 n-tiles).
// A: direct per-lane global loads (+f2bf). B: double-buffered LDS
// [2][128][36] (18.4 KB), one barrier per k-step of 32, loads issued early.
__global__ __launch_bounds__(256) void k_agg(
    const float* __restrict__ RRm, const unsigned short* __restrict__ Et,
    float* __restrict__ part)
{
    __shared__ unsigned short sB[2][128][36];   // pad 36: 18-dword row stride
    const int t = threadIdx.x;
    const int mt = blockIdx.x, b = blockIdx.y, kz = blockIdx.z;
    const int lane = t & 63, wave = t >> 6;
    const int k0 = kz * CHUNK_;

    // B-stage: 128 rows x 32 bf16 per k-step = 512 x 16B chunks; 2 per thread
    const int br0 = t >> 2, bc0 = (t & 3) * 8;       // rows 0..63
    const int br1 = br0 + 64;                        // rows 64..127
    const unsigned short* EtB = Et + (size_t)b * EDP_ * R_;

    // A: two per-lane rows (m-groups), clamped (rows >=1000 dup 999; their
    // part rows are padding, never read by k_obj)
    const int cl = lane & 15, koff = (lane >> 4) * 8;
    int n0 = mt * 128 + wave * 32 + cl;
    int n1 = n0 + 16;
    if (n0 > 999) n0 = 999;
    if (n1 > 999) n1 = 999;
    const float* Ap0 = RRm + ((size_t)(b * O_) + n0) * R_ + k0 + koff;
    const float* Ap1 = RRm + ((size_t)(b * O_) + n1) * R_ + k0 + koff;

    f32x4 acc[2][8] = {};
    float4 a0c, a1c, a2c, a3c;
    float4 a0n = {0,0,0,0}, a1n = {0,0,0,0}, a2n = {0,0,0,0}, a3n = {0,0,0,0};

    // prologue: stage B + load A for iter 0
    {
        ushort8v v0 = *(const ushort8v*)(EtB + (size_t)br0 * R_ + k0 + bc0);
        ushort8v v1 = *(const ushort8v*)(EtB + (size_t)br1 * R_ + k0 + bc0);
        *(ushort8v*)&sB[0][br0][bc0] = v0;
        *(ushort8v*)&sB[0][br1][bc0] = v1;
        a0c = *(const float4*)(Ap0 + 0);
        a1c = *(const float4*)(Ap0 + 4);
        a2c = *(const float4*)(Ap1 + 0);
        a3c = *(const float4*)(Ap1 + 4);
    }
    __syncthreads();

    for (int it = 0; it < CHUNK_ / 32; ++it) {
        const int cur = it & 1, nxt = cur ^ 1;
        const bool more = (it + 1 < CHUNK_ / 32);
        ushort8v v0, v1;
        if (more) {
            // issue next-iter loads EARLY (hide HBM latency under MFMA phase)
            const int kb = k0 + (it + 1) * 32;
            v0 = *(const ushort8v*)(EtB + (size_t)br0 * R_ + kb + bc0);
            v1 = *(const ushort8v*)(EtB + (size_t)br1 * R_ + kb + bc0);
            a0n = *(const float4*)(Ap0 + (it + 1) * 32);
            a1n = *(const float4*)(Ap0 + (it + 1) * 32 + 4);
            a2n = *(const float4*)(Ap1 + (it + 1) * 32);
            a3n = *(const float4*)(Ap1 + (it + 1) * 32 + 4);
        }
        // convert A (cur) to bf16 fragments
        bf16x8 af0, af1;
        af0[0] = (short)f2bf(a0c.x); af0[1] = (short)f2bf(a0c.y);
        af0[2] = (short)f2bf(a0c.z); af0[3] = (short)f2bf(a0c.w);
        af0[4] = (short)f2bf(a1c.x); af0[5] = (short)f2bf(a1c.y);
        af0[6] = (short)f2bf(a1c.z); af0[7] = (short)f2bf(a1c.w);
        af1[0] = (short)f2bf(a2c.x); af1[1] = (short)f2bf(a2c.y);
        af1[2] = (short)f2bf(a2c.z); af1[3] = (short)f2bf(a2c.w);
        af1[4] = (short)f2bf(a3c.x); af1[5] = (short)f2bf(a3c.y);
        af1[6] = (short)f2bf(a3c.z); af1[7] = (short)f2bf(a3c.w);
        #pragma unroll
        for (int ni = 0; ni < 8; ++ni) {
            bf16x8 bf = *(const bf16x8*)&sB[cur][ni * 16 + cl][koff];
            acc[0][ni] = MFMA16(af0, bf, acc[0][ni], 0, 0, 0);
            acc[1][ni] = MFMA16(af1, bf, acc[1][ni], 0, 0, 0);
        }
        if (more) {
            *(ushort8v*)&sB[nxt][br0][bc0] = v0;
            *(ushort8v*)&sB[nxt][br1][bc0] = v1;
        }
        __syncthreads();
        a0c = a0n; a1c = a1n; a2c = a2n; a3c = a3n;
    }

    // store partials: C/D layout col=lane&15, row=(lane>>4)*4+rg
    float* pp = part + ((size_t)(kz * 4 + b) * MPAD_) * 128;
    #pragma unroll
    for (int mg = 0; mg < 2; ++mg) {
        const int rowb = mt * 128 + wave * 32 + mg * 16 + (lane >> 4) * 4;
        #pragma unroll
        for (int ni = 0; ni < 8; ++ni)
            #pragma unroll
            for (int rg = 0; rg < 4; ++rg)
                pp[(size_t)(rowb + rg) * 128 + ni * 16 + cl] = acc[mg][ni][rg];
    }
}

// ---------------- Kernel 4: object MLP (sums agg partials) ------------------
__global__ __launch_bounds__(256) void k_obj(
    const float* __restrict__ obj, const float* __restrict__ part,
    const float* __restrict__ ow1, const float* __restrict__ ob1,
    const float* __restrict__ ow2, const float* __restrict__ ob2,
    float* __restrict__ out)
{
    __shared__ float C[8][112];
    __shared__ float h[8][104];
    const int t = threadIdx.x;
    const int g0 = blockIdx.x * 8;

    for (int idx = t; idx < 8 * NF_; idx += 256) {
        int rr = idx / NF_, f = idx % NF_;
        C[rr][f] = obj[(size_t)(g0 + rr) * NF_ + f];
    }
    for (int idx = t; idx < 8 * 100; idx += 256) {
        int rr = idx / 100, f = idx % 100;
        int g = g0 + rr, b = g / 1000, n = g % 1000;
        float s = 0.f;
        for (int z = 0; z < KS_; ++z)
            s += part[((size_t)(z * 4 + b) * MPAD_ + n) * 128 + f];
        C[rr][6 + f] = s;
    }
    __syncthreads();

    for (int idx = t; idx < 8 * 100; idx += 256) {
        int rr = idx / 100, j = idx % 100;
        float acc = ob1[j];
        for (int k = 0; k < 106; ++k)
            acc = fmaf(C[rr][k], ow1[k * 100 + j], acc);
        h[rr][j] = fmaxf(acc, 0.f);
    }
    __syncthreads();

    if (t < 16) {
        int rr = t >> 1, j = t & 1;
        float acc = ob2[j];
        for (int k = 0; k < 100; ++k)
            acc = fmaf(h[rr][k], ow2[k * 2 + j], acc);
        out[(size_t)(g0 + rr) * 2 + j] = acc;
    }
}

// ---------------- launch ----------------------------------------------------
extern "C" void kernel_launch(void* const* d_in, const int* in_sizes, int n_in,
                              void* d_out, int out_size, void* d_ws, size_t ws_size,
                              hipStream_t stream)
{
    const float* obj   = (const float*)d_in[0];
    const float* S     = (const float*)d_in[1];
    const float* RRm   = (const float*)d_in[2];
    const float* rinfo = (const float*)d_in[3];
    const float* rw1   = (const float*)d_in[4];
    const float* rb1   = (const float*)d_in[5];
    const float* rw2   = (const float*)d_in[6];
    const float* rb2   = (const float*)d_in[7];
    const float* rw3   = (const float*)d_in[8];
    const float* rb3   = (const float*)d_in[9];
    const float* rw4   = (const float*)d_in[10];
    const float* rb4   = (const float*)d_in[11];
    const float* ow1   = (const float*)d_in[12];
    const float* ob1   = (const float*)d_in[13];
    const float* ow2   = (const float*)d_in[14];
    const float* ob2   = (const float*)d_in[15];

    float* ws            = (float*)d_ws;
    float* bmp           = ws;
    unsigned short* Et   = (unsigned short*)(ws + ET_OFF);
    float* part          = ws + PART_OFF;
    unsigned short* Wt   = (unsigned short*)(ws + PART_OFF);  // aliases part head
    float* bfp           = ws + PART_OFF + (WT_USHORTS / 2);
    float* out           = (float*)d_out;

    k_prep<<<dim3(100, 4), 256, 0, stream>>>(rw1, rb1, rw2, rb2, rw3, rb3, rw4, rb4,
                                             Wt, bfp);
    k_marshal<<<dim3(79, 4, 2), 256, 0, stream>>>(obj, S, RRm, rinfo, bmp);
    k_mlp<<<dim3(1250), 256, 0, stream>>>(bmp, Et, Wt, bfp);
    k_agg<<<dim3(8, 4, KS_), 256, 0, stream>>>(RRm, Et, part);
    k_obj<<<dim3(500), 256, 0, stream>>>(obj, part, ow1, ob1, ow2, ob2, out);
}